// Round 1
// baseline (458.096 us; speedup 1.0000x reference)
//
#include <hip/hip_runtime.h>

#define B_   2
#define N_   16384
#define S_   4096
#define D1_  128
#define D2_  256
#define C1_  256
#define C2_  128
#define M_   (B_ * N_)   // 32768 rows

typedef __bf16 bf16_t;
typedef bf16_t bf16x8 __attribute__((ext_vector_type(8)));
typedef float  f32x4  __attribute__((ext_vector_type(4)));

// ---------------------------------------------------------------- helpers
__device__ __forceinline__ void gload16(const void* g, void* l) {
  __builtin_amdgcn_global_load_lds(
      (const __attribute__((address_space(1))) void*)g,
      (__attribute__((address_space(3))) void*)l, 16, 0, 0);
}

// ---------------------------------------------------------------- K0: weights -> bf16, transposed to [N][K]
__global__ __launch_bounds__(256) void prepw_k(const float* __restrict__ w1,
                                               const float* __restrict__ w2,
                                               bf16_t* __restrict__ w1t,
                                               bf16_t* __restrict__ w2t) {
  int i = blockIdx.x * 256 + threadIdx.x;
  if (i < C1_ * 384) {                       // w1t[n][k] = w1[k][n],  [256][384]
    int n = i / 384, k = i % 384;
    w1t[i] = (bf16_t)w1[(size_t)k * C1_ + n];
  } else {
    int j = i - C1_ * 384;                   // w2t[n][k] = w2[k][n],  [128][256]
    if (j < C2_ * C1_) {
      int n = j / C1_, k = j % C1_;
      w2t[j] = (bf16_t)w2[(size_t)k * C2_ + n];
    }
  }
}

// ---------------------------------------------------------------- K1: points2 [B][256][4096] -> p2t [B][4096][256]
__global__ __launch_bounds__(256) void transpose_p2_k(const float* __restrict__ in,
                                                      float* __restrict__ outT) {
  __shared__ float tile[32][33];
  int b  = blockIdx.z;
  int s0 = blockIdx.x * 32, c0 = blockIdx.y * 32;
  int tx = threadIdx.x, ty = threadIdx.y;            // (32, 8)
  const float* src = in + (size_t)b * D2_ * S_;
#pragma unroll
  for (int k = 0; k < 4; ++k)
    tile[ty + k * 8][tx] = src[(size_t)(c0 + ty + k * 8) * S_ + s0 + tx];
  __syncthreads();
  float* dst = outT + (size_t)b * S_ * D2_;
#pragma unroll
  for (int k = 0; k < 4; ++k)
    dst[(size_t)(s0 + ty + k * 8) * D2_ + c0 + tx] = tile[tx][ty + k * 8];
}

// ---------------------------------------------------------------- K1b: points1 [B][128][16384] -> x[r][0:128) bf16 (row stride 384)
__global__ __launch_bounds__(256) void transpose_p1_k(const float* __restrict__ in,
                                                      bf16_t* __restrict__ X) {
  __shared__ float tile[32][33];
  int b  = blockIdx.z;
  int n0 = blockIdx.x * 32, c0 = blockIdx.y * 32;
  int tx = threadIdx.x, ty = threadIdx.y;
  const float* src = in + (size_t)b * D1_ * N_;
#pragma unroll
  for (int k = 0; k < 4; ++k)
    tile[ty + k * 8][tx] = src[(size_t)(c0 + ty + k * 8) * N_ + n0 + tx];
  __syncthreads();
#pragma unroll
  for (int k = 0; k < 4; ++k)
    X[(size_t)(b * N_ + n0 + ty + k * 8) * 384 + c0 + tx] = (bf16_t)tile[tx][ty + k * 8];
}

// ---------------------------------------------------------------- K2: brute-force 3-NN
__global__ __launch_bounds__(256) void knn_k(const float* __restrict__ xyz1,
                                             const float* __restrict__ xyz2,
                                             float* __restrict__ kw,
                                             int* __restrict__ ki) {
  __shared__ float4 pt[1024];
  int tid = threadIdx.x;
  int b   = blockIdx.x >> 6;
  int n   = ((blockIdx.x & 63) << 8) + tid;
  const float* X1 = xyz1 + (size_t)b * 3 * N_;
  const float* X2 = xyz2 + (size_t)b * 3 * S_;
  float ax = X1[n], ay = X1[N_ + n], az = X1[2 * N_ + n];
  float p = ax * ax + ay * ay + az * az;
  float d0 = 3e38f, d1 = 3e38f, d2 = 3e38f;
  int   i0 = 0, i1 = 0, i2 = 0;
  for (int s0 = 0; s0 < S_; s0 += 1024) {
    __syncthreads();
    for (int i = tid; i < 1024; i += 256) {
      float x = X2[s0 + i], y = X2[S_ + s0 + i], z = X2[2 * S_ + s0 + i];
      pt[i] = make_float4(x, y, z, x * x + y * y + z * z);
    }
    __syncthreads();
#pragma unroll 4
    for (int i = 0; i < 1024; ++i) {
      float4 v  = pt[i];
      float dot = ax * v.x + ay * v.y + az * v.z;
      float d   = p - 2.f * dot + v.w;
      d = fmaxf(d, 0.f);
      int s = s0 + i;
      if (d < d2) {
        if (d < d1) {
          d2 = d1; i2 = i1;
          if (d < d0) { d1 = d0; i1 = i0; d0 = d; i0 = s; }
          else        { d1 = d;  i1 = s; }
        } else { d2 = d; i2 = s; }
      }
    }
  }
  d0 = fmaxf(d0, 1e-6f); d1 = fmaxf(d1, 1e-6f); d2 = fmaxf(d2, 1e-6f);
  float r0 = 1.f / d0, r1 = 1.f / d1, r2 = 1.f / d2;
  float dn = fmaxf(r0 + r1 + r2, 1e-6f);
  size_t r = (size_t)b * N_ + n;
  kw[r * 3 + 0] = r0 / dn;  kw[r * 3 + 1] = r1 / dn;  kw[r * 3 + 2] = r2 / dn;
  ki[r * 3 + 0] = i0;       ki[r * 3 + 1] = i1;       ki[r * 3 + 2] = i2;
}

// ---------------------------------------------------------------- K3: weighted gather -> x[r][128:384) bf16
__global__ __launch_bounds__(256) void interp_k(const float* __restrict__ p2t,
                                                const float* __restrict__ kw,
                                                const int* __restrict__ ki,
                                                bf16_t* __restrict__ X) {
  int t  = threadIdx.x;             // channel 0..255
  int p0 = blockIdx.x * 32;
  for (int pp = 0; pp < 32; ++pp) {
    int r = p0 + pp;
    int b = r >> 14;
    float w0 = kw[r * 3 + 0], w1 = kw[r * 3 + 1], w2 = kw[r * 3 + 2];
    int   i0 = ki[r * 3 + 0], i1 = ki[r * 3 + 1], i2 = ki[r * 3 + 2];
    const float* base = p2t + (size_t)b * S_ * D2_;
    float v = w0 * base[(size_t)i0 * D2_ + t]
            + w1 * base[(size_t)i1 * D2_ + t]
            + w2 * base[(size_t)i2 * D2_ + t];
    X[(size_t)r * 384 + 128 + t] = (bf16_t)v;
  }
}

// ---------------------------------------------------------------- K4: GEMM1  [32768x384]@[384x256] + b1 -> y1 bf16
__global__ __launch_bounds__(256) void gemm1_k(const bf16_t* __restrict__ A,
                                               const bf16_t* __restrict__ Bt,
                                               const float* __restrict__ bias,
                                               bf16_t* __restrict__ Y) {
  const int K = 384;
  __shared__ bf16_t As[128 * 32];
  __shared__ bf16_t Bs[128 * 32];
  int tid = threadIdx.x, lane = tid & 63, w = tid >> 6;
  int wr = w >> 1, wc = w & 1;
  int m0 = blockIdx.x * 128, n0 = blockIdx.y * 128;
  int e0 = (w * 2 + 0) * 512 + lane * 8;
  int e1 = (w * 2 + 1) * 512 + lane * 8;
  int ra0 = e0 >> 5, ca0 = e0 & 31;
  int ra1 = e1 >> 5, ca1 = e1 & 31;
  f32x4 acc[4][4];
  f32x4 z = {0.f, 0.f, 0.f, 0.f};
#pragma unroll
  for (int i = 0; i < 4; ++i)
#pragma unroll
    for (int j = 0; j < 4; ++j) acc[i][j] = z;
  for (int k0 = 0; k0 < K; k0 += 32) {
    __syncthreads();
    gload16(A + (size_t)(m0 + ra0) * K + k0 + ca0, &As[e0]);
    gload16(A + (size_t)(m0 + ra1) * K + k0 + ca1, &As[e1]);
    gload16(Bt + (size_t)(n0 + ra0) * K + k0 + ca0, &Bs[e0]);
    gload16(Bt + (size_t)(n0 + ra1) * K + k0 + ca1, &Bs[e1]);
    __syncthreads();
    bf16x8 af[4], bfr[4];
    int arow = wr * 64 + (lane & 15);
    int brow = wc * 64 + (lane & 15);
    int kc = 8 * (lane >> 4);
#pragma unroll
    for (int i = 0; i < 4; ++i) af[i]  = *(const bf16x8*)&As[(arow + i * 16) * 32 + kc];
#pragma unroll
    for (int j = 0; j < 4; ++j) bfr[j] = *(const bf16x8*)&Bs[(brow + j * 16) * 32 + kc];
#pragma unroll
    for (int i = 0; i < 4; ++i)
#pragma unroll
      for (int j = 0; j < 4; ++j)
        acc[i][j] = __builtin_amdgcn_mfma_f32_16x16x32_bf16(af[i], bfr[j], acc[i][j], 0, 0, 0);
  }
#pragma unroll
  for (int j = 0; j < 4; ++j) {
    int col = n0 + wc * 64 + j * 16 + (lane & 15);
    float bv = bias[col];
#pragma unroll
    for (int i = 0; i < 4; ++i) {
      int r = m0 + wr * 64 + i * 16 + ((lane >> 4) << 2);
#pragma unroll
      for (int q = 0; q < 4; ++q)
        Y[(size_t)(r + q) * C1_ + col] = (bf16_t)(acc[i][j][q] + bv);
    }
  }
}

// ---------------------------------------------------------------- K5: per-channel partial sums of y1
__global__ __launch_bounds__(256) void stats1_k(const bf16_t* __restrict__ Y,
                                                float* __restrict__ st) {
  int c  = threadIdx.x;
  int r0 = blockIdx.x * 256;
  float s = 0.f, ss = 0.f;
  for (int r = r0; r < r0 + 256; ++r) {
    float v = (float)Y[(size_t)r * C1_ + c];
    s += v; ss += v * v;
  }
  atomicAdd(&st[c], s);
  atomicAdd(&st[C1_ + c], ss);
}

// ---------------------------------------------------------------- K6: finalize BN1 -> a,s
__global__ void bnfin_k(const float* __restrict__ st, const float* __restrict__ g,
                        const float* __restrict__ be, float* __restrict__ ab,
                        int C, float invM) {
  int c = blockIdx.x * blockDim.x + threadIdx.x;
  if (c >= C) return;
  float mu  = st[c] * invM;
  float var = st[C + c] * invM - mu * mu;
  var = fmaxf(var, 0.f);
  float a = g[c] * rsqrtf(var + 1e-5f);
  ab[c] = a;
  ab[C + c] = be[c] - mu * a;
}

// ---------------------------------------------------------------- K7: x2 = relu(a*y1+s) bf16
__global__ __launch_bounds__(256) void bn1apply_k(const bf16_t* __restrict__ Y,
                                                  const float* __restrict__ ab,
                                                  bf16_t* __restrict__ X2) {
  int t  = threadIdx.x;
  int cc = (t & 31) * 8;
  float a[8], s[8];
#pragma unroll
  for (int u = 0; u < 8; ++u) { a[u] = ab[cc + u]; s[u] = ab[C1_ + cc + u]; }
  int r0 = blockIdx.x * 64 + (t >> 5);
  for (int it = 0; it < 8; ++it) {
    int r = r0 + it * 8;
    bf16x8 v = *(const bf16x8*)&Y[(size_t)r * C1_ + cc];
    bf16x8 o;
#pragma unroll
    for (int u = 0; u < 8; ++u) {
      float f = (float)v[u];
      f = fmaxf(a[u] * f + s[u], 0.f);
      o[u] = (bf16_t)f;
    }
    *(bf16x8*)&X2[(size_t)r * C1_ + cc] = o;
  }
}

// ---------------------------------------------------------------- K8: GEMM2 [32768x256]@[256x128] + b2 -> raw y2, transposed into d_out
__global__ __launch_bounds__(256) void gemm2_k(const bf16_t* __restrict__ A,
                                               const bf16_t* __restrict__ Bt,
                                               const float* __restrict__ bias,
                                               float* __restrict__ OUT) {
  const int K = 256;
  __shared__ bf16_t As[128 * 32];
  __shared__ bf16_t Bs[128 * 32];
  int tid = threadIdx.x, lane = tid & 63, w = tid >> 6;
  int wr = w >> 1, wc = w & 1;
  int m0 = blockIdx.x * 128;
  int e0 = (w * 2 + 0) * 512 + lane * 8;
  int e1 = (w * 2 + 1) * 512 + lane * 8;
  int ra0 = e0 >> 5, ca0 = e0 & 31;
  int ra1 = e1 >> 5, ca1 = e1 & 31;
  f32x4 acc[4][4];
  f32x4 z = {0.f, 0.f, 0.f, 0.f};
#pragma unroll
  for (int i = 0; i < 4; ++i)
#pragma unroll
    for (int j = 0; j < 4; ++j) acc[i][j] = z;
  for (int k0 = 0; k0 < K; k0 += 32) {
    __syncthreads();
    gload16(A + (size_t)(m0 + ra0) * K + k0 + ca0, &As[e0]);
    gload16(A + (size_t)(m0 + ra1) * K + k0 + ca1, &As[e1]);
    gload16(Bt + (size_t)ra0 * K + k0 + ca0, &Bs[e0]);
    gload16(Bt + (size_t)ra1 * K + k0 + ca1, &Bs[e1]);
    __syncthreads();
    bf16x8 af[4], bfr[4];
    int arow = wr * 64 + (lane & 15);
    int brow = wc * 64 + (lane & 15);
    int kc = 8 * (lane >> 4);
#pragma unroll
    for (int i = 0; i < 4; ++i) af[i]  = *(const bf16x8*)&As[(arow + i * 16) * 32 + kc];
#pragma unroll
    for (int j = 0; j < 4; ++j) bfr[j] = *(const bf16x8*)&Bs[(brow + j * 16) * 32 + kc];
#pragma unroll
    for (int i = 0; i < 4; ++i)
#pragma unroll
      for (int j = 0; j < 4; ++j)
        acc[i][j] = __builtin_amdgcn_mfma_f32_16x16x32_bf16(af[i], bfr[j], acc[i][j], 0, 0, 0);
  }
#pragma unroll
  for (int j = 0; j < 4; ++j) {
    int col = wc * 64 + j * 16 + (lane & 15);
    float bv = bias[col];
#pragma unroll
    for (int i = 0; i < 4; ++i) {
      int r  = m0 + wr * 64 + i * 16 + ((lane >> 4) << 2);
      int bb = r >> 14, n = r & (N_ - 1);
      f32x4 v = acc[i][j];
      v[0] += bv; v[1] += bv; v[2] += bv; v[3] += bv;
      *(f32x4*)&OUT[((size_t)(bb * C2_ + col)) * N_ + n] = v;
    }
  }
}

// ---------------------------------------------------------------- K9: per-channel stats of raw y2 (transposed layout) + finalize
__global__ __launch_bounds__(256) void stats2_k(const float* __restrict__ OUT,
                                                const float* __restrict__ g,
                                                const float* __restrict__ be,
                                                float* __restrict__ ab2) {
  int c = blockIdx.x;      // 0..127
  int t = threadIdx.x;     // 256
  float s = 0.f, ss = 0.f;
  for (int b = 0; b < 2; ++b) {
    const float* p = OUT + ((size_t)(b * C2_ + c)) * N_;
    for (int i = t * 4; i < N_; i += 1024) {
      float4 v = *(const float4*)&p[i];
      s  += v.x + v.y + v.z + v.w;
      ss += v.x * v.x + v.y * v.y + v.z * v.z + v.w * v.w;
    }
  }
  __shared__ float rs[4], rss[4];
#pragma unroll
  for (int o = 32; o > 0; o >>= 1) { s += __shfl_down(s, o); ss += __shfl_down(ss, o); }
  if ((t & 63) == 0) { rs[t >> 6] = s; rss[t >> 6] = ss; }
  __syncthreads();
  if (t == 0) {
    s  = rs[0] + rs[1] + rs[2] + rs[3];
    ss = rss[0] + rss[1] + rss[2] + rss[3];
    float mu  = s / (float)M_;
    float var = ss / (float)M_ - mu * mu;
    var = fmaxf(var, 0.f);
    float a = g[c] * rsqrtf(var + 1e-5f);
    ab2[c] = a;
    ab2[C2_ + c] = be[c] - mu * a;
  }
}

// ---------------------------------------------------------------- K10: in-place BN2+ReLU on d_out
__global__ __launch_bounds__(256) void bn2apply_k(float* __restrict__ OUT,
                                                  const float* __restrict__ ab2) {
  size_t i4 = (size_t)blockIdx.x * 256 + threadIdx.x;   // float4 index, 1048576 total
  int c = (int)((i4 >> 12) & 127);
  float a = ab2[c], s = ab2[C2_ + c];
  f32x4 v = *(f32x4*)&OUT[i4 * 4];
#pragma unroll
  for (int u = 0; u < 4; ++u) v[u] = fmaxf(a * v[u] + s, 0.f);
  *(f32x4*)&OUT[i4 * 4] = v;
}

// ---------------------------------------------------------------- launch
extern "C" void kernel_launch(void* const* d_in, const int* in_sizes, int n_in,
                              void* d_out, int out_size, void* d_ws, size_t ws_size,
                              hipStream_t stream) {
  const float* xyz1    = (const float*)d_in[0];
  const float* xyz2    = (const float*)d_in[1];
  const float* points1 = (const float*)d_in[2];
  const float* points2 = (const float*)d_in[3];
  const float* w1      = (const float*)d_in[4];
  const float* b1      = (const float*)d_in[5];
  const float* g1      = (const float*)d_in[6];
  const float* beta1   = (const float*)d_in[7];
  const float* w2      = (const float*)d_in[8];
  const float* b2      = (const float*)d_in[9];
  const float* g2      = (const float*)d_in[10];
  const float* beta2   = (const float*)d_in[11];
  float* out = (float*)d_out;

  char* p = (char*)d_ws;
  size_t off = 0;
  bf16_t* w1t = (bf16_t*)(p + off); off += (size_t)C1_ * 384 * 2;      // 196608
  bf16_t* w2t = (bf16_t*)(p + off); off += (size_t)C2_ * C1_ * 2;      // 65536
  float*  p2t = (float*)(p + off);  off += (size_t)B_ * S_ * D2_ * 4;  // 8388608
  bf16_t* X   = (bf16_t*)(p + off); off += (size_t)M_ * 384 * 2;       // 25165824
  bf16_t* Y1  = (bf16_t*)(p + off); off += (size_t)M_ * C1_ * 2;       // 16777216
  bf16_t* X2  = (bf16_t*)(p + off); off += (size_t)M_ * C1_ * 2;       // 16777216
  float*  KW  = (float*)(p + off);  off += (size_t)M_ * 3 * 4;         // 393216
  int*    KI  = (int*)(p + off);    off += (size_t)M_ * 3 * 4;         // 393216
  float*  ST1 = (float*)(p + off);  off += 2048;
  float*  AB1 = (float*)(p + off);  off += 2048;
  float*  AB2 = (float*)(p + off);  off += 1024;

  hipMemsetAsync(ST1, 0, 2048, stream);

  prepw_k<<<512, 256, 0, stream>>>(w1, w2, w1t, w2t);
  transpose_p2_k<<<dim3(S_ / 32, D2_ / 32, B_), dim3(32, 8), 0, stream>>>(points2, p2t);
  transpose_p1_k<<<dim3(N_ / 32, D1_ / 32, B_), dim3(32, 8), 0, stream>>>(points1, X);
  knn_k<<<128, 256, 0, stream>>>(xyz1, xyz2, KW, KI);
  interp_k<<<1024, 256, 0, stream>>>(p2t, KW, KI, X);
  gemm1_k<<<dim3(M_ / 128, 2), 256, 0, stream>>>(X, w1t, b1, Y1);
  stats1_k<<<128, 256, 0, stream>>>(Y1, ST1);
  bnfin_k<<<1, 256, 0, stream>>>(ST1, g1, beta1, AB1, C1_, 1.f / (float)M_);
  bn1apply_k<<<512, 256, 0, stream>>>(Y1, AB1, X2);
  gemm2_k<<<dim3(M_ / 128, 1), 256, 0, stream>>>(X2, w2t, b2, out);
  stats2_k<<<128, 256, 0, stream>>>(out, g2, beta2, AB2);
  bn2apply_k<<<4096, 256, 0, stream>>>(out, AB2);
}

// Round 2
// 175.496 us; speedup vs baseline: 2.6103x; 2.6103x over previous
//
#include <hip/hip_runtime.h>

#define B_   2
#define N_   16384
#define S_   4096
#define D1_  128
#define D2_  256
#define C1_  256
#define C2_  128
#define M_   (B_ * N_)   // 32768 rows

typedef __bf16 bf16_t;
typedef bf16_t bf16x8 __attribute__((ext_vector_type(8)));
typedef float  f32x4  __attribute__((ext_vector_type(4)));

// ---------------------------------------------------------------- helpers
__device__ __forceinline__ void gload16(const void* g, void* l) {
  __builtin_amdgcn_global_load_lds(
      (const __attribute__((address_space(1))) void*)g,
      (__attribute__((address_space(3))) void*)l, 16, 0, 0);
}

// ---------------------------------------------------------------- K0: weights -> bf16 [N][K]; xyz2 -> c4 = (-2x,-2y,-2z,|c|^2)
__global__ __launch_bounds__(256) void prep_k(const float* __restrict__ w1,
                                              const float* __restrict__ w2,
                                              const float* __restrict__ xyz2,
                                              bf16_t* __restrict__ w1t,
                                              bf16_t* __restrict__ w2t,
                                              float4* __restrict__ c4) {
  int i = blockIdx.x * 256 + threadIdx.x;
  if (i < C1_ * 384) {                       // w1t[n][k] = w1[k][n],  [256][384]
    int n = i / 384, k = i % 384;
    w1t[i] = (bf16_t)w1[(size_t)k * C1_ + n];
  } else if (i < C1_ * 384 + C2_ * C1_) {
    int j = i - C1_ * 384;                   // w2t[n][k] = w2[k][n],  [128][256]
    int n = j / C1_, k = j % C1_;
    w2t[j] = (bf16_t)w2[(size_t)k * C2_ + n];
  } else {
    int j = i - (C1_ * 384 + C2_ * C1_);     // 0 .. B*S-1
    if (j < B_ * S_) {
      int b = j >> 12, s = j & (S_ - 1);
      const float* X2 = xyz2 + (size_t)b * 3 * S_;
      float x = X2[s], y = X2[S_ + s], z = X2[2 * S_ + s];
      c4[j] = make_float4(-2.f * x, -2.f * y, -2.f * z, x * x + y * y + z * z);
    }
  }
}

// ---------------------------------------------------------------- K1: points2 [B][256][4096] -> p2t [B][4096][256]
__global__ __launch_bounds__(256) void transpose_p2_k(const float* __restrict__ in,
                                                      float* __restrict__ outT) {
  __shared__ float tile[32][33];
  int b  = blockIdx.z;
  int s0 = blockIdx.x * 32, c0 = blockIdx.y * 32;
  int tx = threadIdx.x, ty = threadIdx.y;            // (32, 8)
  const float* src = in + (size_t)b * D2_ * S_;
#pragma unroll
  for (int k = 0; k < 4; ++k)
    tile[ty + k * 8][tx] = src[(size_t)(c0 + ty + k * 8) * S_ + s0 + tx];
  __syncthreads();
  float* dst = outT + (size_t)b * S_ * D2_;
#pragma unroll
  for (int k = 0; k < 4; ++k)
    dst[(size_t)(s0 + ty + k * 8) * D2_ + c0 + tx] = tile[tx][ty + k * 8];
}

// ---------------------------------------------------------------- K1b: points1 [B][128][16384] -> x[r][0:128) bf16 (row stride 384)
__global__ __launch_bounds__(256) void transpose_p1_k(const float* __restrict__ in,
                                                      bf16_t* __restrict__ X) {
  __shared__ float tile[32][33];
  int b  = blockIdx.z;
  int n0 = blockIdx.x * 32, c0 = blockIdx.y * 32;
  int tx = threadIdx.x, ty = threadIdx.y;
  const float* src = in + (size_t)b * D1_ * N_;
#pragma unroll
  for (int k = 0; k < 4; ++k)
    tile[ty + k * 8][tx] = src[(size_t)(c0 + ty + k * 8) * N_ + n0 + tx];
  __syncthreads();
#pragma unroll
  for (int k = 0; k < 4; ++k)
    X[(size_t)(b * N_ + n0 + ty + k * 8) * 384 + c0 + tx] = (bf16_t)tile[tx][ty + k * 8];
}

// ---------------------------------------------------------------- K2: brute-force 3-NN, S split 8 ways per query
// block = 512 threads: query q = t&63 (64 per block), chunk = t>>6 (8 chunks of 512 cands)
__global__ __launch_bounds__(512) void knn_k(const float* __restrict__ xyz1,
                                             const float4* __restrict__ c4,
                                             float* __restrict__ kw,
                                             int* __restrict__ ki) {
  __shared__ float sval[8][3][64];
  __shared__ int   sidx[8][3][64];
  int t  = threadIdx.x;
  int q  = t & 63, ch = t >> 6;
  int b  = blockIdx.x >> 8;                       // 256 blocks per batch
  int nb = (blockIdx.x & 255) * 64;
  int n  = nb + q;
  const float* X1 = xyz1 + (size_t)b * 3 * N_;
  float ax = X1[n], ay = X1[N_ + n], az = X1[2 * N_ + n];
  float negp = -(ax * ax + ay * ay + az * az);
  int chU = __builtin_amdgcn_readfirstlane(ch);   // wave-uniform -> scalar loads
  const float4* cc = c4 + (size_t)b * S_ + chU * 512;
  // track val = |c|^2 - 2 dot  (d = p + val); clamp val >= -p  <=>  d >= 0
  float v0 = 3e38f, v1 = 3e38f, v2 = 3e38f;
  int   j0 = 0, j1 = 0, j2 = 0;
#pragma unroll 4
  for (int i = 0; i < 512; ++i) {
    float4 c = cc[i];
    float tt = c.w;
    tt = fmaf(az, c.z, tt);
    tt = fmaf(ay, c.y, tt);
    tt = fmaf(ax, c.x, tt);
    tt = fmaxf(tt, negp);
    if (tt < v2) {
      int s = chU * 512 + i;
      if (tt < v1) {
        v2 = v1; j2 = j1;
        if (tt < v0) { v1 = v0; j1 = j0; v0 = tt; j0 = s; }
        else         { v1 = tt; j1 = s; }
      } else { v2 = tt; j2 = s; }
    }
  }
  sval[ch][0][q] = v0; sval[ch][1][q] = v1; sval[ch][2][q] = v2;
  sidx[ch][0][q] = j0; sidx[ch][1][q] = j1; sidx[ch][2][q] = j2;
  __syncthreads();
  if (t < 64) {
    // merge 8 sorted top-3 lists; chunk order = ascending global index ranges,
    // strict < keeps reference (lex by (d, idx)) tie behavior
    float m0 = 3e38f, m1 = 3e38f, m2 = 3e38f;
    int   a0 = 0, a1 = 0, a2 = 0;
    for (int c = 0; c < 8; ++c)
#pragma unroll
      for (int k = 0; k < 3; ++k) {
        float v = sval[c][k][t]; int ix = sidx[c][k][t];
        if (v < m2) {
          if (v < m1) {
            m2 = m1; a2 = a1;
            if (v < m0) { m1 = m0; a1 = a0; m0 = v; a0 = ix; }
            else        { m1 = v;  a1 = ix; }
          } else { m2 = v; a2 = ix; }
        }
      }
    float p  = -negp;                      // t<64 => q==t, own query's p
    float d0 = fmaxf(p + m0, 1e-6f);
    float d1 = fmaxf(p + m1, 1e-6f);
    float d2 = fmaxf(p + m2, 1e-6f);
    float r0 = 1.f / d0, r1 = 1.f / d1, r2 = 1.f / d2;
    float dn = fmaxf(r0 + r1 + r2, 1e-6f);
    size_t r = (size_t)b * N_ + n;
    kw[r * 3 + 0] = r0 / dn;  kw[r * 3 + 1] = r1 / dn;  kw[r * 3 + 2] = r2 / dn;
    ki[r * 3 + 0] = a0;       ki[r * 3 + 1] = a1;       ki[r * 3 + 2] = a2;
  }
}

// ---------------------------------------------------------------- K3: weighted gather -> x[r][128:384) bf16
__global__ __launch_bounds__(256) void interp_k(const float* __restrict__ p2t,
                                                const float* __restrict__ kw,
                                                const int* __restrict__ ki,
                                                bf16_t* __restrict__ X) {
  int t  = threadIdx.x;             // channel 0..255
  int p0 = blockIdx.x * 32;
  for (int pp = 0; pp < 32; ++pp) {
    int r = p0 + pp;
    int b = r >> 14;
    float w0 = kw[r * 3 + 0], w1 = kw[r * 3 + 1], w2 = kw[r * 3 + 2];
    int   i0 = ki[r * 3 + 0], i1 = ki[r * 3 + 1], i2 = ki[r * 3 + 2];
    const float* base = p2t + (size_t)b * S_ * D2_;
    float v = w0 * base[(size_t)i0 * D2_ + t]
            + w1 * base[(size_t)i1 * D2_ + t]
            + w2 * base[(size_t)i2 * D2_ + t];
    X[(size_t)r * 384 + 128 + t] = (bf16_t)v;
  }
}

// ---------------------------------------------------------------- K4: GEMM1 [32768x384]@[384x256] + b1 -> y1 bf16, fused BN stats
__global__ __launch_bounds__(256) void gemm1_k(const bf16_t* __restrict__ A,
                                               const bf16_t* __restrict__ Bt,
                                               const float* __restrict__ bias,
                                               bf16_t* __restrict__ Y,
                                               float* __restrict__ st) {
  const int K = 384;
  __shared__ bf16_t As[128 * 32];
  __shared__ bf16_t Bs[128 * 32];
  int tid = threadIdx.x, lane = tid & 63, w = tid >> 6;
  int wr = w >> 1, wc = w & 1;
  int m0 = blockIdx.x * 128, n0 = blockIdx.y * 128;
  int e0 = (w * 2 + 0) * 512 + lane * 8;
  int e1 = (w * 2 + 1) * 512 + lane * 8;
  int ra0 = e0 >> 5, ca0 = e0 & 31;
  int ra1 = e1 >> 5, ca1 = e1 & 31;
  f32x4 acc[4][4];
  f32x4 z = {0.f, 0.f, 0.f, 0.f};
#pragma unroll
  for (int i = 0; i < 4; ++i)
#pragma unroll
    for (int j = 0; j < 4; ++j) acc[i][j] = z;
  for (int k0 = 0; k0 < K; k0 += 32) {
    __syncthreads();
    gload16(A + (size_t)(m0 + ra0) * K + k0 + ca0, &As[e0]);
    gload16(A + (size_t)(m0 + ra1) * K + k0 + ca1, &As[e1]);
    gload16(Bt + (size_t)(n0 + ra0) * K + k0 + ca0, &Bs[e0]);
    gload16(Bt + (size_t)(n0 + ra1) * K + k0 + ca1, &Bs[e1]);
    __syncthreads();
    bf16x8 af[4], bfr[4];
    int arow = wr * 64 + (lane & 15);
    int brow = wc * 64 + (lane & 15);
    int kc = 8 * (lane >> 4);
#pragma unroll
    for (int i = 0; i < 4; ++i) af[i]  = *(const bf16x8*)&As[(arow + i * 16) * 32 + kc];
#pragma unroll
    for (int j = 0; j < 4; ++j) bfr[j] = *(const bf16x8*)&Bs[(brow + j * 16) * 32 + kc];
#pragma unroll
    for (int i = 0; i < 4; ++i)
#pragma unroll
      for (int j = 0; j < 4; ++j)
        acc[i][j] = __builtin_amdgcn_mfma_f32_16x16x32_bf16(af[i], bfr[j], acc[i][j], 0, 0, 0);
  }
#pragma unroll
  for (int j = 0; j < 4; ++j) {
    int col = n0 + wc * 64 + j * 16 + (lane & 15);
    float bv = bias[col];
    float sj = 0.f, ssj = 0.f;
#pragma unroll
    for (int i = 0; i < 4; ++i) {
      int r = m0 + wr * 64 + i * 16 + ((lane >> 4) << 2);
#pragma unroll
      for (int q = 0; q < 4; ++q) {
        float y = acc[i][j][q] + bv;
        Y[(size_t)(r + q) * C1_ + col] = (bf16_t)y;
        sj += y; ssj += y * y;
      }
    }
    sj  += __shfl_xor(sj, 16);  sj  += __shfl_xor(sj, 32);
    ssj += __shfl_xor(ssj, 16); ssj += __shfl_xor(ssj, 32);
    if ((lane >> 4) == 0) {
      atomicAdd(&st[col], sj);
      atomicAdd(&st[C1_ + col], ssj);
    }
  }
}

// ---------------------------------------------------------------- K6: finalize BN -> a,s
__global__ void bnfin_k(const float* __restrict__ st, const float* __restrict__ g,
                        const float* __restrict__ be, float* __restrict__ ab,
                        int C, float invM) {
  int c = blockIdx.x * blockDim.x + threadIdx.x;
  if (c >= C) return;
  float mu  = st[c] * invM;
  float var = st[C + c] * invM - mu * mu;
  var = fmaxf(var, 0.f);
  float a = g[c] * rsqrtf(var + 1e-5f);
  ab[c] = a;
  ab[C + c] = be[c] - mu * a;
}

// ---------------------------------------------------------------- K7: x2 = relu(a*y1+s) bf16
__global__ __launch_bounds__(256) void bn1apply_k(const bf16_t* __restrict__ Y,
                                                  const float* __restrict__ ab,
                                                  bf16_t* __restrict__ X2) {
  int t  = threadIdx.x;
  int cc = (t & 31) * 8;
  float a[8], s[8];
#pragma unroll
  for (int u = 0; u < 8; ++u) { a[u] = ab[cc + u]; s[u] = ab[C1_ + cc + u]; }
  int r0 = blockIdx.x * 64 + (t >> 5);
  for (int it = 0; it < 8; ++it) {
    int r = r0 + it * 8;
    bf16x8 v = *(const bf16x8*)&Y[(size_t)r * C1_ + cc];
    bf16x8 o;
#pragma unroll
    for (int u = 0; u < 8; ++u) {
      float f = (float)v[u];
      f = fmaxf(a[u] * f + s[u], 0.f);
      o[u] = (bf16_t)f;
    }
    *(bf16x8*)&X2[(size_t)r * C1_ + cc] = o;
  }
}

// ---------------------------------------------------------------- K8: GEMM2 [32768x256]@[256x128] + b2 -> raw y2 transposed into d_out, fused BN stats
__global__ __launch_bounds__(256) void gemm2_k(const bf16_t* __restrict__ A,
                                               const bf16_t* __restrict__ Bt,
                                               const float* __restrict__ bias,
                                               float* __restrict__ OUT,
                                               float* __restrict__ st) {
  const int K = 256;
  __shared__ bf16_t As[128 * 32];
  __shared__ bf16_t Bs[128 * 32];
  int tid = threadIdx.x, lane = tid & 63, w = tid >> 6;
  int wr = w >> 1, wc = w & 1;
  int m0 = blockIdx.x * 128;
  int e0 = (w * 2 + 0) * 512 + lane * 8;
  int e1 = (w * 2 + 1) * 512 + lane * 8;
  int ra0 = e0 >> 5, ca0 = e0 & 31;
  int ra1 = e1 >> 5, ca1 = e1 & 31;
  f32x4 acc[4][4];
  f32x4 z = {0.f, 0.f, 0.f, 0.f};
#pragma unroll
  for (int i = 0; i < 4; ++i)
#pragma unroll
    for (int j = 0; j < 4; ++j) acc[i][j] = z;
  for (int k0 = 0; k0 < K; k0 += 32) {
    __syncthreads();
    gload16(A + (size_t)(m0 + ra0) * K + k0 + ca0, &As[e0]);
    gload16(A + (size_t)(m0 + ra1) * K + k0 + ca1, &As[e1]);
    gload16(Bt + (size_t)ra0 * K + k0 + ca0, &Bs[e0]);
    gload16(Bt + (size_t)ra1 * K + k0 + ca1, &Bs[e1]);
    __syncthreads();
    bf16x8 af[4], bfr[4];
    int arow = wr * 64 + (lane & 15);
    int brow = wc * 64 + (lane & 15);
    int kc = 8 * (lane >> 4);
#pragma unroll
    for (int i = 0; i < 4; ++i) af[i]  = *(const bf16x8*)&As[(arow + i * 16) * 32 + kc];
#pragma unroll
    for (int j = 0; j < 4; ++j) bfr[j] = *(const bf16x8*)&Bs[(brow + j * 16) * 32 + kc];
#pragma unroll
    for (int i = 0; i < 4; ++i)
#pragma unroll
      for (int j = 0; j < 4; ++j)
        acc[i][j] = __builtin_amdgcn_mfma_f32_16x16x32_bf16(af[i], bfr[j], acc[i][j], 0, 0, 0);
  }
#pragma unroll
  for (int j = 0; j < 4; ++j) {
    int col = wc * 64 + j * 16 + (lane & 15);
    float bv = bias[col];
    float sj = 0.f, ssj = 0.f;
#pragma unroll
    for (int i = 0; i < 4; ++i) {
      int r  = m0 + wr * 64 + i * 16 + ((lane >> 4) << 2);
      int bb = r >> 14, n = r & (N_ - 1);
      f32x4 v = acc[i][j];
#pragma unroll
      for (int q = 0; q < 4; ++q) {
        v[q] += bv;
        sj += v[q]; ssj += v[q] * v[q];
      }
      *(f32x4*)&OUT[((size_t)(bb * C2_ + col)) * N_ + n] = v;
    }
    sj  += __shfl_xor(sj, 16);  sj  += __shfl_xor(sj, 32);
    ssj += __shfl_xor(ssj, 16); ssj += __shfl_xor(ssj, 32);
    if ((lane >> 4) == 0) {
      atomicAdd(&st[col], sj);
      atomicAdd(&st[C2_ + col], ssj);
    }
  }
}

// ---------------------------------------------------------------- K10: in-place BN2+ReLU on d_out
__global__ __launch_bounds__(256) void bn2apply_k(float* __restrict__ OUT,
                                                  const float* __restrict__ ab2) {
  size_t i4 = (size_t)blockIdx.x * 256 + threadIdx.x;   // float4 index, 1048576 total
  int c = (int)((i4 >> 12) & 127);
  float a = ab2[c], s = ab2[C2_ + c];
  f32x4 v = *(f32x4*)&OUT[i4 * 4];
#pragma unroll
  for (int u = 0; u < 4; ++u) v[u] = fmaxf(a * v[u] + s, 0.f);
  *(f32x4*)&OUT[i4 * 4] = v;
}

// ---------------------------------------------------------------- launch
extern "C" void kernel_launch(void* const* d_in, const int* in_sizes, int n_in,
                              void* d_out, int out_size, void* d_ws, size_t ws_size,
                              hipStream_t stream) {
  const float* xyz1    = (const float*)d_in[0];
  const float* xyz2    = (const float*)d_in[1];
  const float* points1 = (const float*)d_in[2];
  const float* points2 = (const float*)d_in[3];
  const float* w1      = (const float*)d_in[4];
  const float* b1      = (const float*)d_in[5];
  const float* g1      = (const float*)d_in[6];
  const float* beta1   = (const float*)d_in[7];
  const float* w2      = (const float*)d_in[8];
  const float* b2      = (const float*)d_in[9];
  const float* g2      = (const float*)d_in[10];
  const float* beta2   = (const float*)d_in[11];
  float* out = (float*)d_out;

  char* p = (char*)d_ws;
  size_t off = 0;
  bf16_t* w1t = (bf16_t*)(p + off); off += (size_t)C1_ * 384 * 2;      // 196608
  bf16_t* w2t = (bf16_t*)(p + off); off += (size_t)C2_ * C1_ * 2;      // 65536
  float*  p2t = (float*)(p + off);  off += (size_t)B_ * S_ * D2_ * 4;  // 8388608
  bf16_t* X   = (bf16_t*)(p + off); off += (size_t)M_ * 384 * 2;       // 25165824
  bf16_t* Y1  = (bf16_t*)(p + off); off += (size_t)M_ * C1_ * 2;       // 16777216
  bf16_t* X2  = (bf16_t*)(p + off); off += (size_t)M_ * C1_ * 2;       // 16777216
  float4* C4  = (float4*)(p + off); off += (size_t)B_ * S_ * 16;       // 131072
  float*  KW  = (float*)(p + off);  off += (size_t)M_ * 3 * 4;         // 393216
  int*    KI  = (int*)(p + off);    off += (size_t)M_ * 3 * 4;         // 393216
  float*  ST1 = (float*)(p + off);  off += 2048;                       // 256 sum + 256 ss
  float*  ST2 = (float*)(p + off);  off += 1024;                       // 128 sum + 128 ss
  float*  AB1 = (float*)(p + off);  off += 2048;
  float*  AB2 = (float*)(p + off);  off += 1024;

  hipMemsetAsync(ST1, 0, 3072, stream);   // ST1 + ST2 contiguous

  prep_k<<<544, 256, 0, stream>>>(w1, w2, xyz2, w1t, w2t, C4);
  transpose_p2_k<<<dim3(S_ / 32, D2_ / 32, B_), dim3(32, 8), 0, stream>>>(points2, p2t);
  transpose_p1_k<<<dim3(N_ / 32, D1_ / 32, B_), dim3(32, 8), 0, stream>>>(points1, X);
  knn_k<<<512, 512, 0, stream>>>(xyz1, C4, KW, KI);
  interp_k<<<1024, 256, 0, stream>>>(p2t, KW, KI, X);
  gemm1_k<<<dim3(M_ / 128, 2), 256, 0, stream>>>(X, w1t, b1, Y1, ST1);
  bnfin_k<<<1, 256, 0, stream>>>(ST1, g1, beta1, AB1, C1_, 1.f / (float)M_);
  bn1apply_k<<<512, 256, 0, stream>>>(Y1, AB1, X2);
  gemm2_k<<<dim3(M_ / 128, 1), 256, 0, stream>>>(X2, w2t, b2, out, ST2);
  bnfin_k<<<1, 128, 0, stream>>>(ST2, g2, beta2, AB2, C2_, 1.f / (float)M_);
  bn2apply_k<<<4096, 256, 0, stream>>>(out, AB2);
}

// Round 3
// 151.746 us; speedup vs baseline: 3.0188x; 1.1565x over previous
//
#include <hip/hip_runtime.h>

#define B_   2
#define N_   16384
#define S_   4096
#define D1_  128
#define D2_  256
#define C1_  256
#define C2_  128
#define M_   (B_ * N_)   // 32768 rows

typedef __bf16 bf16_t;
typedef bf16_t bf16x8 __attribute__((ext_vector_type(8)));
typedef bf16_t bf16x4 __attribute__((ext_vector_type(4)));
typedef float  f32x4  __attribute__((ext_vector_type(4)));

// ---------------------------------------------------------------- helpers
__device__ __forceinline__ void gload16(const void* g, void* l) {
  __builtin_amdgcn_global_load_lds(
      (const __attribute__((address_space(1))) void*)g,
      (__attribute__((address_space(3))) void*)l, 16, 0, 0);
}

__device__ __forceinline__ float med3f(float a, float b, float c) {
  float d;
  asm("v_med3_f32 %0, %1, %2, %3" : "=v"(d) : "v"(a), "v"(b), "v"(c));
  return d;
}

// ---------------------------------------------------------------- K0: setup — transposes + weight prep + c4
// blocks [0,2048): points2 transpose -> p2t [B][4096][256]
// blocks [2048,6144): points1 transpose -> X[r][0:128) bf16 (row stride 384)
// blocks [6144,6688): w1t/w2t bf16 [N][K] + c4 = (-2x,-2y,-2z,|c|^2)
__global__ __launch_bounds__(256) void setup_k(const float* __restrict__ points2,
                                               const float* __restrict__ points1,
                                               const float* __restrict__ w1,
                                               const float* __restrict__ w2,
                                               const float* __restrict__ xyz2,
                                               float* __restrict__ p2t,
                                               bf16_t* __restrict__ X,
                                               bf16_t* __restrict__ w1t,
                                               bf16_t* __restrict__ w2t,
                                               float4* __restrict__ c4) {
  __shared__ float tile[32][33];
  int bi = blockIdx.x, t = threadIdx.x;
  int tx = t & 31, ty = t >> 5;
  if (bi < 2048) {
    int b = bi >> 10, rest = bi & 1023;
    int s0 = (rest & 127) * 32, c0 = (rest >> 7) * 32;
    const float* src = points2 + (size_t)b * D2_ * S_;
#pragma unroll
    for (int k = 0; k < 4; ++k)
      tile[ty + k * 8][tx] = src[(size_t)(c0 + ty + k * 8) * S_ + s0 + tx];
    __syncthreads();
    float* dst = p2t + (size_t)b * S_ * D2_;
#pragma unroll
    for (int k = 0; k < 4; ++k)
      dst[(size_t)(s0 + ty + k * 8) * D2_ + c0 + tx] = tile[tx][ty + k * 8];
  } else if (bi < 6144) {
    int bj = bi - 2048;
    int b = bj >> 11, rest = bj & 2047;
    int n0 = (rest & 511) * 32, c0 = (rest >> 9) * 32;
    const float* src = points1 + (size_t)b * D1_ * N_;
#pragma unroll
    for (int k = 0; k < 4; ++k)
      tile[ty + k * 8][tx] = src[(size_t)(c0 + ty + k * 8) * N_ + n0 + tx];
    __syncthreads();
#pragma unroll
    for (int k = 0; k < 4; ++k)
      X[(size_t)(b * N_ + n0 + ty + k * 8) * 384 + c0 + tx] = (bf16_t)tile[tx][ty + k * 8];
  } else {
    int i = (bi - 6144) * 256 + t;
    if (i < C1_ * 384) {                       // w1t[n][k] = w1[k][n]
      int n = i / 384, k = i % 384;
      w1t[i] = (bf16_t)w1[(size_t)k * C1_ + n];
    } else if (i < C1_ * 384 + C2_ * C1_) {
      int j = i - C1_ * 384;                   // w2t[n][k] = w2[k][n]
      int n = j / C1_, k = j % C1_;
      w2t[j] = (bf16_t)w2[(size_t)k * C2_ + n];
    } else {
      int j = i - (C1_ * 384 + C2_ * C1_);     // 0 .. B*S-1
      if (j < B_ * S_) {
        int b = j >> 12, s = j & (S_ - 1);
        const float* X2p = xyz2 + (size_t)b * 3 * S_;
        float x = X2p[s], y = X2p[S_ + s], z = X2p[2 * S_ + s];
        c4[j] = make_float4(-2.f * x, -2.f * y, -2.f * z, x * x + y * y + z * z);
      }
    }
  }
}

// ---------------------------------------------------------------- K1: 3-NN + fused weighted gather
// 512 blocks, 512 threads. Block handles 64 queries x full S.
// Wave w owns candidate chunk [w*512,(w+1)*512) staged in LDS (64KB).
__global__ __launch_bounds__(512) void knn_k(const float* __restrict__ xyz1,
                                             const float4* __restrict__ c4,
                                             const float* __restrict__ p2t,
                                             bf16_t* __restrict__ X) {
  __shared__ char lds[65536];
  int t = threadIdx.x, l = t & 63, w = t >> 6;
  int b  = blockIdx.x >> 8;                    // 256 blocks per batch
  int nb = (blockIdx.x & 255) * 64;
  // stage all 4096 candidates (float4 each) into LDS
  const float4* cb = c4 + (size_t)b * S_;
#pragma unroll
  for (int k = 0; k < 8; ++k)
    gload16(cb + t + 512 * k, lds + (size_t)(t + 512 * k) * 16);
  int n = nb + l;
  const float* X1 = xyz1 + (size_t)b * 3 * N_;
  float ax = X1[n], ay = X1[N_ + n], az = X1[2 * N_ + n];
  float negp = -(ax * ax + ay * ay + az * az);
  __syncthreads();
  const float4* cc = (const float4*)lds + w * 512;
  int base = w * 512;
  float m0 = 3e38f, m1 = 3e38f, m2 = 3e38f;
  int   j0 = 0, j1 = 0, j2 = 0;
#pragma unroll 4
  for (int i = 0; i < 512; ++i) {
    float4 c = cc[i];
    float v = c.w;
    v = fmaf(az, c.z, v);
    v = fmaf(ay, c.y, v);
    v = fmaf(ax, c.x, v);
    v = fmaxf(v, negp);                        // d = p + v clamped at 0
    int idx = base + i;
    bool b0 = v < m0, b1 = v < m1, b2 = v < m2;
    float nm0 = fminf(v, m0);
    float nm1 = med3f(m0, v, m1);
    float nm2 = med3f(m1, v, m2);
    j2 = b1 ? j1 : (b2 ? idx : j2);
    j1 = b0 ? j0 : (b1 ? idx : j1);
    j0 = b0 ? idx : j0;
    m0 = nm0; m1 = nm1; m2 = nm2;
  }
  __syncthreads();                             // all waves done with candidate LDS
  float* SV = (float*)lds;                     // [8][3][64]
  int*   SI = (int*)(lds + 6144);              // [8][3][64]
  float* QW = (float*)(lds + 12288);           // [64][3]
  int*   QI = (int*)(lds + 13056);             // [64][3]
  SV[(w * 3 + 0) * 64 + l] = m0;  SV[(w * 3 + 1) * 64 + l] = m1;  SV[(w * 3 + 2) * 64 + l] = m2;
  SI[(w * 3 + 0) * 64 + l] = j0;  SI[(w * 3 + 1) * 64 + l] = j1;  SI[(w * 3 + 2) * 64 + l] = j2;
  __syncthreads();
  if (t < 64) {
    // merge 8 sorted top-3 lists in ascending-chunk order (strict <, stable)
    float M0 = 3e38f, M1 = 3e38f, M2 = 3e38f;
    int   a0 = 0, a1 = 0, a2 = 0;
    for (int ch = 0; ch < 8; ++ch)
#pragma unroll
      for (int k = 0; k < 3; ++k) {
        float v = SV[(ch * 3 + k) * 64 + t];
        int  ix = SI[(ch * 3 + k) * 64 + t];
        bool b0 = v < M0, b1 = v < M1, b2 = v < M2;
        float nm0 = fminf(v, M0);
        float nm1 = med3f(M0, v, M1);
        float nm2 = med3f(M1, v, M2);
        a2 = b1 ? a1 : (b2 ? ix : a2);
        a1 = b0 ? a0 : (b1 ? ix : a1);
        a0 = b0 ? ix : a0;
        M0 = nm0; M1 = nm1; M2 = nm2;
      }
    float p  = -negp;                          // t<64: own query's |x1|^2
    float d0 = fmaxf(p + M0, 1e-6f);
    float d1 = fmaxf(p + M1, 1e-6f);
    float d2 = fmaxf(p + M2, 1e-6f);
    float r0 = 1.f / d0, r1 = 1.f / d1, r2 = 1.f / d2;
    float dn = fmaxf(r0 + r1 + r2, 1e-6f);
    QW[t * 3 + 0] = r0 / dn;  QW[t * 3 + 1] = r1 / dn;  QW[t * 3 + 2] = r2 / dn;
    QI[t * 3 + 0] = a0;       QI[t * 3 + 1] = a1;       QI[t * 3 + 2] = a2;
  }
  __syncthreads();
  // fused gather: 64 queries x 256 channels; thread -> (q = t>>3, 32-ch segment)
  int q  = t >> 3, sg = (t & 7) * 32;
  float w0 = QW[q * 3 + 0], w1 = QW[q * 3 + 1], w2 = QW[q * 3 + 2];
  int   i0 = QI[q * 3 + 0], i1 = QI[q * 3 + 1], i2 = QI[q * 3 + 2];
  const float* pb = p2t + (size_t)b * S_ * D2_;
  const float4* r0p = (const float4*)(pb + (size_t)i0 * D2_ + sg);
  const float4* r1p = (const float4*)(pb + (size_t)i1 * D2_ + sg);
  const float4* r2p = (const float4*)(pb + (size_t)i2 * D2_ + sg);
  size_t row = (size_t)b * N_ + nb + q;
  bf16_t* xo = X + row * 384 + 128 + sg;
#pragma unroll
  for (int it = 0; it < 8; ++it) {
    float4 A = r0p[it], Bv = r1p[it], Cv = r2p[it];
    bf16x4 o;
    o[0] = (bf16_t)(w0 * A.x + w1 * Bv.x + w2 * Cv.x);
    o[1] = (bf16_t)(w0 * A.y + w1 * Bv.y + w2 * Cv.y);
    o[2] = (bf16_t)(w0 * A.z + w1 * Bv.z + w2 * Cv.z);
    o[3] = (bf16_t)(w0 * A.w + w1 * Bv.w + w2 * Cv.w);
    *(bf16x4*)&xo[it * 4] = o;
  }
}

// ---------------------------------------------------------------- K2: GEMM1 [32768x384]@[384x256] + b1 -> y1 bf16, fused BN stats
__global__ __launch_bounds__(256) void gemm1_k(const bf16_t* __restrict__ A,
                                               const bf16_t* __restrict__ Bt,
                                               const float* __restrict__ bias,
                                               bf16_t* __restrict__ Y,
                                               float* __restrict__ st) {
  const int K = 384;
  __shared__ bf16_t As[128 * 32];
  __shared__ bf16_t Bs[128 * 32];
  int tid = threadIdx.x, lane = tid & 63, w = tid >> 6;
  int wr = w >> 1, wc = w & 1;
  int m0 = blockIdx.x * 128, n0 = blockIdx.y * 128;
  int e0 = (w * 2 + 0) * 512 + lane * 8;
  int e1 = (w * 2 + 1) * 512 + lane * 8;
  int ra0 = e0 >> 5, ca0 = e0 & 31;
  int ra1 = e1 >> 5, ca1 = e1 & 31;
  f32x4 acc[4][4];
  f32x4 z = {0.f, 0.f, 0.f, 0.f};
#pragma unroll
  for (int i = 0; i < 4; ++i)
#pragma unroll
    for (int j = 0; j < 4; ++j) acc[i][j] = z;
  for (int k0 = 0; k0 < K; k0 += 32) {
    __syncthreads();
    gload16(A + (size_t)(m0 + ra0) * K + k0 + ca0, &As[e0]);
    gload16(A + (size_t)(m0 + ra1) * K + k0 + ca1, &As[e1]);
    gload16(Bt + (size_t)(n0 + ra0) * K + k0 + ca0, &Bs[e0]);
    gload16(Bt + (size_t)(n0 + ra1) * K + k0 + ca1, &Bs[e1]);
    __syncthreads();
    bf16x8 af[4], bfr[4];
    int arow = wr * 64 + (lane & 15);
    int brow = wc * 64 + (lane & 15);
    int kc = 8 * (lane >> 4);
#pragma unroll
    for (int i = 0; i < 4; ++i) af[i]  = *(const bf16x8*)&As[(arow + i * 16) * 32 + kc];
#pragma unroll
    for (int j = 0; j < 4; ++j) bfr[j] = *(const bf16x8*)&Bs[(brow + j * 16) * 32 + kc];
#pragma unroll
    for (int i = 0; i < 4; ++i)
#pragma unroll
      for (int j = 0; j < 4; ++j)
        acc[i][j] = __builtin_amdgcn_mfma_f32_16x16x32_bf16(af[i], bfr[j], acc[i][j], 0, 0, 0);
  }
#pragma unroll
  for (int j = 0; j < 4; ++j) {
    int col = n0 + wc * 64 + j * 16 + (lane & 15);
    float bv = bias[col];
    float sj = 0.f, ssj = 0.f;
#pragma unroll
    for (int i = 0; i < 4; ++i) {
      int r = m0 + wr * 64 + i * 16 + ((lane >> 4) << 2);
#pragma unroll
      for (int q = 0; q < 4; ++q) {
        float y = acc[i][j][q] + bv;
        Y[(size_t)(r + q) * C1_ + col] = (bf16_t)y;
        sj += y; ssj += y * y;
      }
    }
    sj  += __shfl_xor(sj, 16);  sj  += __shfl_xor(sj, 32);
    ssj += __shfl_xor(ssj, 16); ssj += __shfl_xor(ssj, 32);
    if ((lane >> 4) == 0) {
      atomicAdd(&st[col], sj);
      atomicAdd(&st[C1_ + col], ssj);
    }
  }
}

// ---------------------------------------------------------------- K3: x2 = relu(a*y1+s) bf16 (BN finalize folded in)
__global__ __launch_bounds__(256) void bn1apply_k(const bf16_t* __restrict__ Y,
                                                  const float* __restrict__ st,
                                                  const float* __restrict__ g,
                                                  const float* __restrict__ be,
                                                  bf16_t* __restrict__ X2) {
  __shared__ float sa[256], sb[256];
  int t = threadIdx.x;
  {
    const float invM = 1.f / (float)M_;
    float mu  = st[t] * invM;
    float var = fmaxf(st[C1_ + t] * invM - mu * mu, 0.f);
    float a = g[t] * rsqrtf(var + 1e-5f);
    sa[t] = a;
    sb[t] = be[t] - mu * a;
  }
  __syncthreads();
  int cc = (t & 31) * 8;
  float a[8], s[8];
#pragma unroll
  for (int u = 0; u < 8; ++u) { a[u] = sa[cc + u]; s[u] = sb[cc + u]; }
  int r0 = blockIdx.x * 64 + (t >> 5);
  for (int it = 0; it < 8; ++it) {
    int r = r0 + it * 8;
    bf16x8 v = *(const bf16x8*)&Y[(size_t)r * C1_ + cc];
    bf16x8 o;
#pragma unroll
    for (int u = 0; u < 8; ++u) {
      float f = (float)v[u];
      f = fmaxf(a[u] * f + s[u], 0.f);
      o[u] = (bf16_t)f;
    }
    *(bf16x8*)&X2[(size_t)r * C1_ + cc] = o;
  }
}

// ---------------------------------------------------------------- K4: GEMM2 [32768x256]@[256x128] + b2 -> raw y2 transposed into d_out, fused BN stats
__global__ __launch_bounds__(256) void gemm2_k(const bf16_t* __restrict__ A,
                                               const bf16_t* __restrict__ Bt,
                                               const float* __restrict__ bias,
                                               float* __restrict__ OUT,
                                               float* __restrict__ st) {
  const int K = 256;
  __shared__ bf16_t As[128 * 32];
  __shared__ bf16_t Bs[128 * 32];
  int tid = threadIdx.x, lane = tid & 63, w = tid >> 6;
  int wr = w >> 1, wc = w & 1;
  int m0 = blockIdx.x * 128;
  int e0 = (w * 2 + 0) * 512 + lane * 8;
  int e1 = (w * 2 + 1) * 512 + lane * 8;
  int ra0 = e0 >> 5, ca0 = e0 & 31;
  int ra1 = e1 >> 5, ca1 = e1 & 31;
  f32x4 acc[4][4];
  f32x4 z = {0.f, 0.f, 0.f, 0.f};
#pragma unroll
  for (int i = 0; i < 4; ++i)
#pragma unroll
    for (int j = 0; j < 4; ++j) acc[i][j] = z;
  for (int k0 = 0; k0 < K; k0 += 32) {
    __syncthreads();
    gload16(A + (size_t)(m0 + ra0) * K + k0 + ca0, &As[e0]);
    gload16(A + (size_t)(m0 + ra1) * K + k0 + ca1, &As[e1]);
    gload16(Bt + (size_t)ra0 * K + k0 + ca0, &Bs[e0]);
    gload16(Bt + (size_t)ra1 * K + k0 + ca1, &Bs[e1]);
    __syncthreads();
    bf16x8 af[4], bfr[4];
    int arow = wr * 64 + (lane & 15);
    int brow = wc * 64 + (lane & 15);
    int kc = 8 * (lane >> 4);
#pragma unroll
    for (int i = 0; i < 4; ++i) af[i]  = *(const bf16x8*)&As[(arow + i * 16) * 32 + kc];
#pragma unroll
    for (int j = 0; j < 4; ++j) bfr[j] = *(const bf16x8*)&Bs[(brow + j * 16) * 32 + kc];
#pragma unroll
    for (int i = 0; i < 4; ++i)
#pragma unroll
      for (int j = 0; j < 4; ++j)
        acc[i][j] = __builtin_amdgcn_mfma_f32_16x16x32_bf16(af[i], bfr[j], acc[i][j], 0, 0, 0);
  }
#pragma unroll
  for (int j = 0; j < 4; ++j) {
    int col = wc * 64 + j * 16 + (lane & 15);
    float bv = bias[col];
    float sj = 0.f, ssj = 0.f;
#pragma unroll
    for (int i = 0; i < 4; ++i) {
      int r  = m0 + wr * 64 + i * 16 + ((lane >> 4) << 2);
      int bb = r >> 14, n = r & (N_ - 1);
      f32x4 v = acc[i][j];
#pragma unroll
      for (int q = 0; q < 4; ++q) {
        v[q] += bv;
        sj += v[q]; ssj += v[q] * v[q];
      }
      *(f32x4*)&OUT[((size_t)(bb * C2_ + col)) * N_ + n] = v;
    }
    sj  += __shfl_xor(sj, 16);  sj  += __shfl_xor(sj, 32);
    ssj += __shfl_xor(ssj, 16); ssj += __shfl_xor(ssj, 32);
    if ((lane >> 4) == 0) {
      atomicAdd(&st[col], sj);
      atomicAdd(&st[C2_ + col], ssj);
    }
  }
}

// ---------------------------------------------------------------- K5: in-place BN2+ReLU on d_out (BN finalize folded in)
__global__ __launch_bounds__(256) void bn2apply_k(float* __restrict__ OUT,
                                                  const float* __restrict__ st,
                                                  const float* __restrict__ g,
                                                  const float* __restrict__ be) {
  __shared__ float ab[2];
  int t = threadIdx.x;
  int c = (blockIdx.x >> 4) & 127;             // 16 blocks per (b,c) row
  if (t == 0) {
    const float invM = 1.f / (float)M_;
    float mu  = st[c] * invM;
    float var = fmaxf(st[C2_ + c] * invM - mu * mu, 0.f);
    float a = g[c] * rsqrtf(var + 1e-5f);
    ab[0] = a;
    ab[1] = be[c] - mu * a;
  }
  __syncthreads();
  float a = ab[0], s = ab[1];
  size_t i4 = (size_t)blockIdx.x * 256 + t;    // float4 index
  f32x4 v = *(f32x4*)&OUT[i4 * 4];
#pragma unroll
  for (int u = 0; u < 4; ++u) v[u] = fmaxf(a * v[u] + s, 0.f);
  *(f32x4*)&OUT[i4 * 4] = v;
}

// ---------------------------------------------------------------- launch
extern "C" void kernel_launch(void* const* d_in, const int* in_sizes, int n_in,
                              void* d_out, int out_size, void* d_ws, size_t ws_size,
                              hipStream_t stream) {
  const float* xyz1    = (const float*)d_in[0];
  const float* xyz2    = (const float*)d_in[1];
  const float* points1 = (const float*)d_in[2];
  const float* points2 = (const float*)d_in[3];
  const float* w1      = (const float*)d_in[4];
  const float* b1      = (const float*)d_in[5];
  const float* g1      = (const float*)d_in[6];
  const float* beta1   = (const float*)d_in[7];
  const float* w2      = (const float*)d_in[8];
  const float* b2      = (const float*)d_in[9];
  const float* g2      = (const float*)d_in[10];
  const float* beta2   = (const float*)d_in[11];
  float* out = (float*)d_out;

  char* p = (char*)d_ws;
  size_t off = 0;
  bf16_t* w1t = (bf16_t*)(p + off); off += (size_t)C1_ * 384 * 2;      // 196608
  bf16_t* w2t = (bf16_t*)(p + off); off += (size_t)C2_ * C1_ * 2;      // 65536
  float*  p2t = (float*)(p + off);  off += (size_t)B_ * S_ * D2_ * 4;  // 8388608
  bf16_t* X   = (bf16_t*)(p + off); off += (size_t)M_ * 384 * 2;       // 25165824
  bf16_t* Y1  = (bf16_t*)(p + off); off += (size_t)M_ * C1_ * 2;       // 16777216
  bf16_t* X2  = (bf16_t*)(p + off); off += (size_t)M_ * C1_ * 2;       // 16777216
  float4* C4  = (float4*)(p + off); off += (size_t)B_ * S_ * 16;       // 131072
  float*  ST1 = (float*)(p + off);  off += 2048;                       // 256 sum + 256 ss
  float*  ST2 = (float*)(p + off);  off += 1024;                       // 128 sum + 128 ss

  hipMemsetAsync(ST1, 0, 3072, stream);   // ST1 + ST2 contiguous

  setup_k<<<6688, 256, 0, stream>>>(points2, points1, w1, w2, xyz2, p2t, X, w1t, w2t, C4);
  knn_k<<<512, 512, 0, stream>>>(xyz1, C4, p2t, X);
  gemm1_k<<<dim3(M_ / 128, 2), 256, 0, stream>>>(X, w1t, b1, Y1, ST1);
  bn1apply_k<<<512, 256, 0, stream>>>(Y1, ST1, g1, beta1, X2);
  gemm2_k<<<M_ / 128, 256, 0, stream>>>(X2, w2t, b2, out, ST2);
  bn2apply_k<<<4096, 256, 0, stream>>>(out, ST2, g2, beta2);
}

// Round 4
// 143.997 us; speedup vs baseline: 3.1813x; 1.0538x over previous
//
#include <hip/hip_runtime.h>

#define B_   2
#define N_   16384
#define S_   4096
#define D1_  128
#define D2_  256
#define C1_  256
#define C2_  128
#define M_   (B_ * N_)   // 32768 rows

typedef __bf16 bf16_t;
typedef bf16_t bf16x8 __attribute__((ext_vector_type(8)));
typedef bf16_t bf16x4 __attribute__((ext_vector_type(4)));
typedef float  f32x4  __attribute__((ext_vector_type(4)));

// ---------------------------------------------------------------- helpers
__device__ __forceinline__ void gload16(const void* g, void* l) {
  __builtin_amdgcn_global_load_lds(
      (const __attribute__((address_space(1))) void*)g,
      (__attribute__((address_space(3))) void*)l, 16, 0, 0);
}

__device__ __forceinline__ float med3f(float a, float b, float c) {
  float d;
  asm("v_med3_f32 %0, %1, %2, %3" : "=v"(d) : "v"(a), "v"(b), "v"(c));
  return d;
}

// ---------------------------------------------------------------- K0: setup — transposes + weight prep + c4
// blocks [0,2048): points2 transpose -> p2t [B][4096][256]
// blocks [2048,6144): points1 transpose -> X[r][0:128) bf16 (row stride 384)
// blocks [6144,6688): w1t/w2t bf16 [N][K] + c4 = (-2x,-2y,-2z,|c|^2)
__global__ __launch_bounds__(256) void setup_k(const float* __restrict__ points2,
                                               const float* __restrict__ points1,
                                               const float* __restrict__ w1,
                                               const float* __restrict__ w2,
                                               const float* __restrict__ xyz2,
                                               float* __restrict__ p2t,
                                               bf16_t* __restrict__ X,
                                               bf16_t* __restrict__ w1t,
                                               bf16_t* __restrict__ w2t,
                                               float4* __restrict__ c4) {
  __shared__ float tile[32][33];
  int bi = blockIdx.x, t = threadIdx.x;
  int tx = t & 31, ty = t >> 5;
  if (bi < 2048) {
    int b = bi >> 10, rest = bi & 1023;
    int s0 = (rest & 127) * 32, c0 = (rest >> 7) * 32;
    const float* src = points2 + (size_t)b * D2_ * S_;
#pragma unroll
    for (int k = 0; k < 4; ++k)
      tile[ty + k * 8][tx] = src[(size_t)(c0 + ty + k * 8) * S_ + s0 + tx];
    __syncthreads();
    float* dst = p2t + (size_t)b * S_ * D2_;
#pragma unroll
    for (int k = 0; k < 4; ++k)
      dst[(size_t)(s0 + ty + k * 8) * D2_ + c0 + tx] = tile[tx][ty + k * 8];
  } else if (bi < 6144) {
    int bj = bi - 2048;
    int b = bj >> 11, rest = bj & 2047;
    int n0 = (rest & 511) * 32, c0 = (rest >> 9) * 32;
    const float* src = points1 + (size_t)b * D1_ * N_;
#pragma unroll
    for (int k = 0; k < 4; ++k)
      tile[ty + k * 8][tx] = src[(size_t)(c0 + ty + k * 8) * N_ + n0 + tx];
    __syncthreads();
#pragma unroll
    for (int k = 0; k < 4; ++k)
      X[(size_t)(b * N_ + n0 + ty + k * 8) * 384 + c0 + tx] = (bf16_t)tile[tx][ty + k * 8];
  } else {
    int i = (bi - 6144) * 256 + t;
    if (i < C1_ * 384) {                       // w1t[n][k] = w1[k][n]
      int n = i / 384, k = i % 384;
      w1t[i] = (bf16_t)w1[(size_t)k * C1_ + n];
    } else if (i < C1_ * 384 + C2_ * C1_) {
      int j = i - C1_ * 384;                   // w2t[n][k] = w2[k][n]
      int n = j / C1_, k = j % C1_;
      w2t[j] = (bf16_t)w2[(size_t)k * C2_ + n];
    } else {
      int j = i - (C1_ * 384 + C2_ * C1_);     // 0 .. B*S-1
      if (j < B_ * S_) {
        int b = j >> 12, s = j & (S_ - 1);
        const float* X2p = xyz2 + (size_t)b * 3 * S_;
        float x = X2p[s], y = X2p[S_ + s], z = X2p[2 * S_ + s];
        c4[j] = make_float4(-2.f * x, -2.f * y, -2.f * z, x * x + y * y + z * z);
      }
    }
  }
}

// ---------------------------------------------------------------- K1: 3-NN + fused weighted gather
// 1024 blocks x 512 threads. Block: 32 queries x full S.
// lane l: query q = l&31, half h = l>>5; slice s = w*2+h in [0,16).
// Candidates staged in 4 rounds of 1024 (16KB) -> 4 blocks/CU, 8 waves/SIMD.
__global__ __launch_bounds__(512, 8) void knn_k(const float* __restrict__ xyz1,
                                                const float4* __restrict__ c4,
                                                const float* __restrict__ p2t,
                                                bf16_t* __restrict__ X) {
  __shared__ float4 cbuf[1024];                 // 16KB staging; reused for partials
  __shared__ float  T3V[2][3][32];
  __shared__ int    T3I[2][3][32];
  __shared__ float  QWs[32][3];
  __shared__ int    QIs[32][3];
  int t = threadIdx.x, l = t & 63, w = t >> 6;
  int q = l & 31, h = l >> 5;
  int s = w * 2 + h;                            // slice 0..15
  int b  = blockIdx.x >> 9;                     // 512 blocks per batch
  int nb = (blockIdx.x & 511) * 32;
  int n  = nb + q;
  const float* X1 = xyz1 + (size_t)b * 3 * N_;
  float ax = X1[n], ay = X1[N_ + n], az = X1[2 * N_ + n];
  float negp = -(ax * ax + ay * ay + az * az);
  const float4* cb = c4 + (size_t)b * S_;
  float m0 = 3e38f, m1 = 3e38f, m2 = 3e38f;
  int   j0 = 0, j1 = 0, j2 = 0;
  for (int r = 0; r < 4; ++r) {
    __syncthreads();                            // prev round's scan done
    gload16(cb + r * 1024 + t,       (char*)cbuf + (size_t)t * 16);
    gload16(cb + r * 1024 + t + 512, (char*)cbuf + (size_t)(t + 512) * 16);
    __syncthreads();                            // staged data visible
    const float4* cs = cbuf + s * 64;
    int base = r * 1024 + s * 64;
#pragma unroll 4
    for (int i = 0; i < 64; ++i) {
      float4 c = cs[i];
      float v = c.w;
      v = fmaf(az, c.z, v);
      v = fmaf(ay, c.y, v);
      v = fmaf(ax, c.x, v);
      v = fmaxf(v, negp);                       // d = p + v clamped at 0
      int idx = base + i;
      bool b0 = v < m0, b1 = v < m1, b2 = v < m2;
      float nm0 = fminf(v, m0);
      float nm1 = med3f(m0, v, m1);
      float nm2 = med3f(m1, v, m2);
      j2 = b1 ? j1 : (b2 ? idx : j2);
      j1 = b0 ? j0 : (b1 ? idx : j1);
      j0 = b0 ? idx : j0;
      m0 = nm0; m1 = nm1; m2 = nm2;
    }
  }
  __syncthreads();                              // all scans done; reuse cbuf
  float* SV = (float*)cbuf;                     // [16][3][32] = 6KB
  int*   SI = (int*)cbuf + 1536;                // [16][3][32] = 6KB
  SV[(s * 3 + 0) * 32 + q] = m0;  SV[(s * 3 + 1) * 32 + q] = m1;  SV[(s * 3 + 2) * 32 + q] = m2;
  SI[(s * 3 + 0) * 32 + q] = j0;  SI[(s * 3 + 1) * 32 + q] = j1;  SI[(s * 3 + 2) * 32 + q] = j2;
  __syncthreads();
  if (t < 64) {                                 // stage A: merge 8 slices each
    int th = t >> 5, tq = t & 31;
    float M0 = 3e38f, M1 = 3e38f, M2 = 3e38f;
    int   a0 = 0, a1 = 0, a2 = 0;
    for (int s2 = th * 8; s2 < th * 8 + 8; ++s2)
#pragma unroll
      for (int k = 0; k < 3; ++k) {
        float v = SV[(s2 * 3 + k) * 32 + tq];
        int  ix = SI[(s2 * 3 + k) * 32 + tq];
        bool b0 = v < M0, b1 = v < M1, b2 = v < M2;
        float nm0 = fminf(v, M0);
        float nm1 = med3f(M0, v, M1);
        float nm2 = med3f(M1, v, M2);
        a2 = b1 ? a1 : (b2 ? ix : a2);
        a1 = b0 ? a0 : (b1 ? ix : a1);
        a0 = b0 ? ix : a0;
        M0 = nm0; M1 = nm1; M2 = nm2;
      }
    T3V[th][0][tq] = M0; T3V[th][1][tq] = M1; T3V[th][2][tq] = M2;
    T3I[th][0][tq] = a0; T3I[th][1][tq] = a1; T3I[th][2][tq] = a2;
  }
  __syncthreads();
  if (t < 32) {                                 // stage B: final merge; t == own query
    float M0 = T3V[0][0][t], M1 = T3V[0][1][t], M2 = T3V[0][2][t];
    int   a0 = T3I[0][0][t], a1 = T3I[0][1][t], a2 = T3I[0][2][t];
#pragma unroll
    for (int k = 0; k < 3; ++k) {
      float v = T3V[1][k][t];
      int  ix = T3I[1][k][t];
      bool b0 = v < M0, b1 = v < M1, b2 = v < M2;
      float nm0 = fminf(v, M0);
      float nm1 = med3f(M0, v, M1);
      float nm2 = med3f(M1, v, M2);
      a2 = b1 ? a1 : (b2 ? ix : a2);
      a1 = b0 ? a0 : (b1 ? ix : a1);
      a0 = b0 ? ix : a0;
      M0 = nm0; M1 = nm1; M2 = nm2;
    }
    float p  = -negp;                           // t<32 -> w=0,h=0,q=t: own query
    float d0 = fmaxf(p + M0, 1e-6f);
    float d1 = fmaxf(p + M1, 1e-6f);
    float d2 = fmaxf(p + M2, 1e-6f);
    float r0 = 1.f / d0, r1 = 1.f / d1, r2 = 1.f / d2;
    float dn = fmaxf(r0 + r1 + r2, 1e-6f);
    QWs[t][0] = r0 / dn;  QWs[t][1] = r1 / dn;  QWs[t][2] = r2 / dn;
    QIs[t][0] = a0;       QIs[t][1] = a1;       QIs[t][2] = a2;
  }
  __syncthreads();
  // fused gather: 32 queries x 256 channels; thread -> (q = t>>4, 16-ch segment)
  int gq = t >> 4, c0 = (t & 15) * 16;
  float w0 = QWs[gq][0], w1 = QWs[gq][1], w2 = QWs[gq][2];
  int   i0 = QIs[gq][0], i1 = QIs[gq][1], i2 = QIs[gq][2];
  const float* pb = p2t + (size_t)b * S_ * D2_;
  bf16_t* xo = X + ((size_t)(b * N_ + nb + gq)) * 384 + 128 + c0;
#pragma unroll
  for (int u = 0; u < 4; ++u) {
    float4 A  = *(const float4*)(pb + (size_t)i0 * D2_ + c0 + u * 4);
    float4 Bv = *(const float4*)(pb + (size_t)i1 * D2_ + c0 + u * 4);
    float4 Cv = *(const float4*)(pb + (size_t)i2 * D2_ + c0 + u * 4);
    bf16x4 o;
    o[0] = (bf16_t)(w0 * A.x + w1 * Bv.x + w2 * Cv.x);
    o[1] = (bf16_t)(w0 * A.y + w1 * Bv.y + w2 * Cv.y);
    o[2] = (bf16_t)(w0 * A.z + w1 * Bv.z + w2 * Cv.z);
    o[3] = (bf16_t)(w0 * A.w + w1 * Bv.w + w2 * Cv.w);
    *(bf16x4*)&xo[u * 4] = o;
  }
}

// ---------------------------------------------------------------- K2: GEMM1 [32768x384]@[384x256] + b1 -> y1 bf16, fused BN stats
__global__ __launch_bounds__(256) void gemm1_k(const bf16_t* __restrict__ A,
                                               const bf16_t* __restrict__ Bt,
                                               const float* __restrict__ bias,
                                               bf16_t* __restrict__ Y,
                                               float* __restrict__ st) {
  const int K = 384;
  __shared__ bf16_t As[128 * 32];
  __shared__ bf16_t Bs[128 * 32];
  int tid = threadIdx.x, lane = tid & 63, w = tid >> 6;
  int wr = w >> 1, wc = w & 1;
  int m0 = blockIdx.x * 128, n0 = blockIdx.y * 128;
  int e0 = (w * 2 + 0) * 512 + lane * 8;
  int e1 = (w * 2 + 1) * 512 + lane * 8;
  int ra0 = e0 >> 5, ca0 = e0 & 31;
  int ra1 = e1 >> 5, ca1 = e1 & 31;
  f32x4 acc[4][4];
  f32x4 z = {0.f, 0.f, 0.f, 0.f};
#pragma unroll
  for (int i = 0; i < 4; ++i)
#pragma unroll
    for (int j = 0; j < 4; ++j) acc[i][j] = z;
  for (int k0 = 0; k0 < K; k0 += 32) {
    __syncthreads();
    gload16(A + (size_t)(m0 + ra0) * K + k0 + ca0, &As[e0]);
    gload16(A + (size_t)(m0 + ra1) * K + k0 + ca1, &As[e1]);
    gload16(Bt + (size_t)(n0 + ra0) * K + k0 + ca0, &Bs[e0]);
    gload16(Bt + (size_t)(n0 + ra1) * K + k0 + ca1, &Bs[e1]);
    __syncthreads();
    bf16x8 af[4], bfr[4];
    int arow = wr * 64 + (lane & 15);
    int brow = wc * 64 + (lane & 15);
    int kc = 8 * (lane >> 4);
#pragma unroll
    for (int i = 0; i < 4; ++i) af[i]  = *(const bf16x8*)&As[(arow + i * 16) * 32 + kc];
#pragma unroll
    for (int j = 0; j < 4; ++j) bfr[j] = *(const bf16x8*)&Bs[(brow + j * 16) * 32 + kc];
#pragma unroll
    for (int i = 0; i < 4; ++i)
#pragma unroll
      for (int j = 0; j < 4; ++j)
        acc[i][j] = __builtin_amdgcn_mfma_f32_16x16x32_bf16(af[i], bfr[j], acc[i][j], 0, 0, 0);
  }
#pragma unroll
  for (int j = 0; j < 4; ++j) {
    int col = n0 + wc * 64 + j * 16 + (lane & 15);
    float bv = bias[col];
    float sj = 0.f, ssj = 0.f;
#pragma unroll
    for (int i = 0; i < 4; ++i) {
      int r = m0 + wr * 64 + i * 16 + ((lane >> 4) << 2);
#pragma unroll
      for (int q = 0; q < 4; ++q) {
        float y = acc[i][j][q] + bv;
        Y[(size_t)(r + q) * C1_ + col] = (bf16_t)y;
        sj += y; ssj += y * y;
      }
    }
    sj  += __shfl_xor(sj, 16);  sj  += __shfl_xor(sj, 32);
    ssj += __shfl_xor(ssj, 16); ssj += __shfl_xor(ssj, 32);
    if ((lane >> 4) == 0) {
      atomicAdd(&st[col], sj);
      atomicAdd(&st[C1_ + col], ssj);
    }
  }
}

// ---------------------------------------------------------------- K3: x2 = relu(a*y1+s) bf16 (BN finalize folded in)
__global__ __launch_bounds__(256) void bn1apply_k(const bf16_t* __restrict__ Y,
                                                  const float* __restrict__ st,
                                                  const float* __restrict__ g,
                                                  const float* __restrict__ be,
                                                  bf16_t* __restrict__ X2) {
  __shared__ float sa[256], sb[256];
  int t = threadIdx.x;
  {
    const float invM = 1.f / (float)M_;
    float mu  = st[t] * invM;
    float var = fmaxf(st[C1_ + t] * invM - mu * mu, 0.f);
    float a = g[t] * rsqrtf(var + 1e-5f);
    sa[t] = a;
    sb[t] = be[t] - mu * a;
  }
  __syncthreads();
  int cc = (t & 31) * 8;
  float a[8], s[8];
#pragma unroll
  for (int u = 0; u < 8; ++u) { a[u] = sa[cc + u]; s[u] = sb[cc + u]; }
  int r0 = blockIdx.x * 64 + (t >> 5);
  for (int it = 0; it < 8; ++it) {
    int r = r0 + it * 8;
    bf16x8 v = *(const bf16x8*)&Y[(size_t)r * C1_ + cc];
    bf16x8 o;
#pragma unroll
    for (int u = 0; u < 8; ++u) {
      float f = (float)v[u];
      f = fmaxf(a[u] * f + s[u], 0.f);
      o[u] = (bf16_t)f;
    }
    *(bf16x8*)&X2[(size_t)r * C1_ + cc] = o;
  }
}

// ---------------------------------------------------------------- K4: GEMM2 [32768x256]@[256x128] + b2 -> raw y2 transposed into d_out, fused BN stats
__global__ __launch_bounds__(256) void gemm2_k(const bf16_t* __restrict__ A,
                                               const bf16_t* __restrict__ Bt,
                                               const float* __restrict__ bias,
                                               float* __restrict__ OUT,
                                               float* __restrict__ st) {
  const int K = 256;
  __shared__ bf16_t As[128 * 32];
  __shared__ bf16_t Bs[128 * 32];
  int tid = threadIdx.x, lane = tid & 63, w = tid >> 6;
  int wr = w >> 1, wc = w & 1;
  int m0 = blockIdx.x * 128;
  int e0 = (w * 2 + 0) * 512 + lane * 8;
  int e1 = (w * 2 + 1) * 512 + lane * 8;
  int ra0 = e0 >> 5, ca0 = e0 & 31;
  int ra1 = e1 >> 5, ca1 = e1 & 31;
  f32x4 acc[4][4];
  f32x4 z = {0.f, 0.f, 0.f, 0.f};
#pragma unroll
  for (int i = 0; i < 4; ++i)
#pragma unroll
    for (int j = 0; j < 4; ++j) acc[i][j] = z;
  for (int k0 = 0; k0 < K; k0 += 32) {
    __syncthreads();
    gload16(A + (size_t)(m0 + ra0) * K + k0 + ca0, &As[e0]);
    gload16(A + (size_t)(m0 + ra1) * K + k0 + ca1, &As[e1]);
    gload16(Bt + (size_t)ra0 * K + k0 + ca0, &Bs[e0]);
    gload16(Bt + (size_t)ra1 * K + k0 + ca1, &Bs[e1]);
    __syncthreads();
    bf16x8 af[4], bfr[4];
    int arow = wr * 64 + (lane & 15);
    int brow = wc * 64 + (lane & 15);
    int kc = 8 * (lane >> 4);
#pragma unroll
    for (int i = 0; i < 4; ++i) af[i]  = *(const bf16x8*)&As[(arow + i * 16) * 32 + kc];
#pragma unroll
    for (int j = 0; j < 4; ++j) bfr[j] = *(const bf16x8*)&Bs[(brow + j * 16) * 32 + kc];
#pragma unroll
    for (int i = 0; i < 4; ++i)
#pragma unroll
      for (int j = 0; j < 4; ++j)
        acc[i][j] = __builtin_amdgcn_mfma_f32_16x16x32_bf16(af[i], bfr[j], acc[i][j], 0, 0, 0);
  }
#pragma unroll
  for (int j = 0; j < 4; ++j) {
    int col = wc * 64 + j * 16 + (lane & 15);
    float bv = bias[col];
    float sj = 0.f, ssj = 0.f;
#pragma unroll
    for (int i = 0; i < 4; ++i) {
      int r  = m0 + wr * 64 + i * 16 + ((lane >> 4) << 2);
      int bb = r >> 14, n = r & (N_ - 1);
      f32x4 v = acc[i][j];
#pragma unroll
      for (int q = 0; q < 4; ++q) {
        v[q] += bv;
        sj += v[q]; ssj += v[q] * v[q];
      }
      *(f32x4*)&OUT[((size_t)(bb * C2_ + col)) * N_ + n] = v;
    }
    sj  += __shfl_xor(sj, 16);  sj  += __shfl_xor(sj, 32);
    ssj += __shfl_xor(ssj, 16); ssj += __shfl_xor(ssj, 32);
    if ((lane >> 4) == 0) {
      atomicAdd(&st[col], sj);
      atomicAdd(&st[C2_ + col], ssj);
    }
  }
}

// ---------------------------------------------------------------- K5: in-place BN2+ReLU on d_out (BN finalize folded in)
__global__ __launch_bounds__(256) void bn2apply_k(float* __restrict__ OUT,
                                                  const float* __restrict__ st,
                                                  const float* __restrict__ g,
                                                  const float* __restrict__ be) {
  __shared__ float ab[2];
  int t = threadIdx.x;
  int c = (blockIdx.x >> 4) & 127;             // 16 blocks per (b,c) row
  if (t == 0) {
    const float invM = 1.f / (float)M_;
    float mu  = st[c] * invM;
    float var = fmaxf(st[C2_ + c] * invM - mu * mu, 0.f);
    float a = g[c] * rsqrtf(var + 1e-5f);
    ab[0] = a;
    ab[1] = be[c] - mu * a;
  }
  __syncthreads();
  float a = ab[0], s = ab[1];
  size_t i4 = (size_t)blockIdx.x * 256 + t;    // float4 index
  f32x4 v = *(f32x4*)&OUT[i4 * 4];
#pragma unroll
  for (int u = 0; u < 4; ++u) v[u] = fmaxf(a * v[u] + s, 0.f);
  *(f32x4*)&OUT[i4 * 4] = v;
}

// ---------------------------------------------------------------- launch
extern "C" void kernel_launch(void* const* d_in, const int* in_sizes, int n_in,
                              void* d_out, int out_size, void* d_ws, size_t ws_size,
                              hipStream_t stream) {
  const float* xyz1    = (const float*)d_in[0];
  const float* xyz2    = (const float*)d_in[1];
  const float* points1 = (const float*)d_in[2];
  const float* points2 = (const float*)d_in[3];
  const float* w1      = (const float*)d_in[4];
  const float* b1      = (const float*)d_in[5];
  const float* g1      = (const float*)d_in[6];
  const float* beta1   = (const float*)d_in[7];
  const float* w2      = (const float*)d_in[8];
  const float* b2      = (const float*)d_in[9];
  const float* g2      = (const float*)d_in[10];
  const float* beta2   = (const float*)d_in[11];
  float* out = (float*)d_out;

  char* p = (char*)d_ws;
  size_t off = 0;
  bf16_t* w1t = (bf16_t*)(p + off); off += (size_t)C1_ * 384 * 2;      // 196608
  bf16_t* w2t = (bf16_t*)(p + off); off += (size_t)C2_ * C1_ * 2;      // 65536
  float*  p2t = (float*)(p + off);  off += (size_t)B_ * S_ * D2_ * 4;  // 8388608
  bf16_t* X   = (bf16_t*)(p + off); off += (size_t)M_ * 384 * 2;       // 25165824
  bf16_t* Y1  = (bf16_t*)(p + off); off += (size_t)M_ * C1_ * 2;       // 16777216
  bf16_t* X2  = (bf16_t*)(p + off); off += (size_t)M_ * C1_ * 2;       // 16777216
  float4* C4  = (float4*)(p + off); off += (size_t)B_ * S_ * 16;       // 131072
  float*  ST1 = (float*)(p + off);  off += 2048;                       // 256 sum + 256 ss
  float*  ST2 = (float*)(p + off);  off += 1024;                       // 128 sum + 128 ss

  hipMemsetAsync(ST1, 0, 3072, stream);   // ST1 + ST2 contiguous

  setup_k<<<6688, 256, 0, stream>>>(points2, points1, w1, w2, xyz2, p2t, X, w1t, w2t, C4);
  knn_k<<<1024, 512, 0, stream>>>(xyz1, C4, p2t, X);
  gemm1_k<<<dim3(M_ / 128, 2), 256, 0, stream>>>(X, w1t, b1, Y1, ST1);
  bn1apply_k<<<512, 256, 0, stream>>>(Y1, ST1, g1, beta1, X2);
  gemm2_k<<<M_ / 128, 256, 0, stream>>>(X2, w2t, b2, out, ST2);
  bn2apply_k<<<4096, 256, 0, stream>>>(out, ST2, g2, beta2);
}